// Round 4
// baseline (306.512 us; speedup 1.0000x reference)
//
#include <hip/hip_runtime.h>

#define N_TOK 16384
#define D 64
#define NC 512
#define KSEL 16

// ---------------- kernel P0: zero out + zero hist + center norms ----------------
__global__ void prep_kernel(float4* __restrict__ out4, int* __restrict__ hist,
                            const float* __restrict__ ctrs, float* __restrict__ c2) {
    int i = blockIdx.x * 256 + threadIdx.x;
    out4[i] = make_float4(0.f, 0.f, 0.f, 0.f);
    if (i < NC) {
        const float4* row = (const float4*)(ctrs + i * D);
        float s = 0.f;
        #pragma unroll
        for (int q = 0; q < D / 4; ++q) {
            float4 v = row[q];
            s += v.x * v.x + v.y * v.y + v.z * v.z + v.w * v.w;
        }
        c2[i] = s;
    } else if (i < 2 * NC) {
        hist[i - NC] = 0;
    }
}

__device__ __forceinline__ unsigned fkey(float f) {
    unsigned u = __float_as_uint(f);
    return (u & 0x80000000u) ? ~u : (u | 0x80000000u);
}
__device__ __forceinline__ float funkey(unsigned k) {
    unsigned u = (k & 0x80000000u) ? (k & 0x7fffffffu) : ~k;
    return __uint_as_float(u);
}

// ---------------- kernel B: dist + top-16 + softmax, lane = token ----------------
// 512 threads = 8 waves; 64 tokens/block (lane L <-> token base+L, shared by all
// waves); wave wi handles centers {p*64 + wi*8 .. +7} over 8 phases.
// All 512 scores/token live in registers (64/lane/wave); selection is pure VALU.
// Keys: fkey(score) with low 9 bits replaced by center id (globally unique).
__global__ __launch_bounds__(512, 2) void topk5_kernel(
    const float* __restrict__ x, const float* __restrict__ ctrs,
    const float* __restrict__ c2, float* __restrict__ scores,
    int* __restrict__ sidx, int* __restrict__ hist) {
    __shared__ __align__(16) unsigned char pool[35840];
    float* xs = (float*)pool;                 // [64][68]  17408 B
    float* slab = (float*)(pool + 17408);     // [64][64]  16384 B (phase centers)
    int* lhist = (int*)(pool + 33792);        // [512]      2048 B
    unsigned* mb = (unsigned*)pool;           // [64][132] 33792 B, overlays xs+slab

    const int t = threadIdx.x;
    const int lane = t & 63;
    const int wi = t >> 6;
    const int base = blockIdx.x * 64;

    for (int i = t; i < NC; i += 512) lhist[i] = 0;

    // stage x tile -> xs (stride 68, coalesced writes)
    #pragma unroll
    for (int i = 0; i < 2; ++i) {
        int e = t + 512 * i;
        int r = e >> 4, j = e & 15;
        float4 v = *(const float4*)(x + (base + r) * D + j * 4);
        *(float4*)(xs + r * 68 + j * 4) = v;
    }
    __syncthreads();

    // own token's x row -> 64 VGPRs
    float xr[64];
    #pragma unroll
    for (int q = 0; q < 16; ++q) {
        float4 v = *(const float4*)(xs + lane * 68 + q * 4);
        xr[4 * q + 0] = v.x; xr[4 * q + 1] = v.y;
        xr[4 * q + 2] = v.z; xr[4 * q + 3] = v.w;
    }

    unsigned skey[64];

    // prefetch phase 0 centers into regs
    float4 pre0, pre1;
    {
        int e0 = t, r0 = e0 >> 4, j0 = e0 & 15;
        pre0 = *(const float4*)(ctrs + r0 * D + j0 * 4);
        int e1 = t + 512, r1 = e1 >> 4, j1 = e1 & 15;
        pre1 = *(const float4*)(ctrs + (64 + r1 & 0x7fffffff, r1) * 0 + r1 * D + j1 * 4 + 512 * 4); // placeholder removed below
    }
    // (re-do cleanly to avoid any confusion)
    {
        int e1 = t + 512, r1 = e1 >> 4, j1 = e1 & 15;
        pre1 = *(const float4*)(ctrs + r1 * D + j1 * 4);
    }

    #pragma unroll
    for (int p = 0; p < 8; ++p) {
        __syncthreads();  // slab free (previous phase's compute done)
        {
            int e0 = t, r0 = e0 >> 4, j0 = e0 & 15;
            *(float4*)(slab + r0 * D + j0 * 4) = pre0;
            int e1 = t + 512, r1 = e1 >> 4, j1 = e1 & 15;
            *(float4*)(slab + r1 * D + j1 * 4) = pre1;
        }
        if (p < 7) {  // prefetch next phase while computing this one
            int e0 = t, r0 = e0 >> 4, j0 = e0 & 15;
            pre0 = *(const float4*)(ctrs + ((p + 1) * 64 + r0) * D + j0 * 4);
            int e1 = t + 512, r1 = e1 >> 4, j1 = e1 & 15;
            pre1 = *(const float4*)(ctrs + ((p + 1) * 64 + r1) * D + j1 * 4);
        }
        __syncthreads();  // slab ready

        #pragma unroll
        for (int jc = 0; jc < 8; ++jc) {
            const float* row = slab + (wi * 8 + jc) * D;  // wave-uniform: broadcast
            float a = 0.f;
            #pragma unroll
            for (int q = 0; q < 16; ++q) {
                float4 w = *(const float4*)(row + q * 4);
                a = fmaf(xr[4 * q + 0], w.x, a);
                a = fmaf(xr[4 * q + 1], w.y, a);
                a = fmaf(xr[4 * q + 2], w.z, a);
                a = fmaf(xr[4 * q + 3], w.w, a);
            }
            int cg = p * 64 + wi * 8 + jc;
            float sc = fmaf(2.f, a, -c2[cg]);   // c2 load is wave-uniform -> scalar
            skey[p * 8 + jc] = (fkey(sc) & 0xFFFFFE00u) | (unsigned)cg;
        }
    }

    // per-lane top-16 of this wave's 64 keys: masked descending extraction
    unsigned outk[16];
    {
        unsigned prev = 0xFFFFFFFFu;
        #pragma unroll
        for (int r = 0; r < KSEL; ++r) {
            unsigned m = 0u;
            #pragma unroll
            for (int j = 0; j < 64; ++j) {
                unsigned tv = (skey[j] < prev) ? skey[j] : 0u;
                m = m > tv ? m : tv;
            }
            outk[r] = m;
            prev = m;
        }
    }

    __syncthreads();  // all slab reads done; xs dead -> mb overlay safe
    {
        uint4* dst = (uint4*)(mb + lane * 132 + wi * 16);
        dst[0] = make_uint4(outk[0], outk[1], outk[2], outk[3]);
        dst[1] = make_uint4(outk[4], outk[5], outk[6], outk[7]);
        dst[2] = make_uint4(outk[8], outk[9], outk[10], outk[11]);
        dst[3] = make_uint4(outk[12], outk[13], outk[14], outk[15]);
    }
    __syncthreads();

    if (wi == 0) {  // 8-way tournament merge per lane (= per token), exact
        unsigned h[8]; int pos[8];
        #pragma unroll
        for (int w = 0; w < 8; ++w) { pos[w] = 0; h[w] = mb[lane * 132 + w * 16]; }
        float vals[16]; int ids[16];
        #pragma unroll
        for (int r = 0; r < KSEL; ++r) {
            unsigned m = h[0];
            #pragma unroll
            for (int w = 1; w < 8; ++w) m = m > h[w] ? m : h[w];
            vals[r] = funkey(m);
            ids[r] = (int)(m & 511u);
            #pragma unroll
            for (int w = 0; w < 8; ++w) {
                if (h[w] == m) {  // keys globally unique -> exactly one hit
                    ++pos[w];
                    h[w] = (pos[w] < KSEL) ? mb[lane * 132 + w * 16 + pos[w]] : 0u;
                }
            }
        }
        float mx = vals[0];
        float e[16]; float sum = 0.f;
        #pragma unroll
        for (int r = 0; r < KSEL; ++r) { e[r] = __expf(vals[r] - mx); sum += e[r]; }
        float inv = 1.f / sum;
        int n = base + lane;
        #pragma unroll
        for (int q = 0; q < 4; ++q) {
            *(float4*)(scores + n * KSEL + 4 * q) =
                make_float4(e[4*q] * inv, e[4*q+1] * inv, e[4*q+2] * inv, e[4*q+3] * inv);
            *(int4*)(sidx + n * KSEL + 4 * q) =
                make_int4(ids[4*q], ids[4*q+1], ids[4*q+2], ids[4*q+3]);
        }
        #pragma unroll
        for (int r = 0; r < KSEL; ++r) atomicAdd(&lhist[ids[r]], 1);
    }
    __syncthreads();
    for (int i = t; i < NC; i += 512) { int hv = lhist[i]; if (hv) atomicAdd(&hist[i], hv); }
}

// ---------------- kernel S: prefix scan of hist (single block) ----------------
__global__ __launch_bounds__(512) void scan_kernel(const int* __restrict__ hist,
                                                   int* __restrict__ offs,
                                                   int* __restrict__ cursor) {
    __shared__ int buf[2][NC];
    int t = threadIdx.x;
    int self = hist[t];
    buf[0][t] = self;
    __syncthreads();
    int a = 0;
    for (int d = 1; d < NC; d <<= 1) {
        int val = buf[a][t] + (t >= d ? buf[a][t - d] : 0);
        buf[1 - a][t] = val;
        __syncthreads();
        a = 1 - a;
    }
    int incl = buf[a][t];
    int excl = incl - self;
    offs[t] = excl;
    cursor[t] = excl;
    if (t == NC - 1) offs[NC] = incl;
}

// ---------------- kernel P: counting-sort scatter, 256 blocks ----------------
__global__ __launch_bounds__(256) void scatter4_kernel(
    const int* __restrict__ sidx, const float* __restrict__ scores,
    int* __restrict__ cursor, int* __restrict__ tokentab,
    float* __restrict__ scotab) {
    __shared__ int lh[NC];
    __shared__ int lbase[NC];
    const int t = threadIdx.x;
    for (int i = t; i < NC; i += 256) lh[i] = 0;
    __syncthreads();
    const int base_e = blockIdx.x * 1024;
    int myc[4];
    #pragma unroll
    for (int i = 0; i < 4; ++i) {
        int c = sidx[base_e + t + 256 * i];
        myc[i] = c;
        atomicAdd(&lh[c], 1);
    }
    __syncthreads();
    for (int i = t; i < NC; i += 256) {
        int h = lh[i];
        lbase[i] = h ? atomicAdd(&cursor[i], h) : 0;
        lh[i] = 0;
    }
    __syncthreads();
    #pragma unroll
    for (int i = 0; i < 4; ++i) {
        int e = base_e + t + 256 * i;
        int c = myc[i];
        int pos = lbase[c] + atomicAdd(&lh[c], 1);
        tokentab[pos] = (c << 16) | (e >> 4);
        scotab[pos] = scores[e];
    }
}

// ---------------- kernel C: chunk-balanced affine mixing ----------------
// One wave per 64 consecutive center-sorted pairs. W[.][lane] in 64 VGPRs,
// reloaded on (rare) center change; (token,score) pre-loaded and shfl-broadcast.
__global__ __launch_bounds__(256) void mix4_kernel(
    const float* __restrict__ x, const float* __restrict__ Wv,
    const float* __restrict__ Ov, const int* __restrict__ tokentab,
    const float* __restrict__ scotab, float* __restrict__ out) {
    const int lane = threadIdx.x & 63;
    const int gw = blockIdx.x * 4 + (threadIdx.x >> 6);   // 0..4095
    const int i0 = gw * 64;

    int word_v = tokentab[i0 + lane];
    float sco_v = scotab[i0 + lane];

    float w[64];
    float ovl = 0.f;
    int cur = -1;

    #pragma unroll 1
    for (int ii = 0; ii < 64; ++ii) {
        int word = __builtin_amdgcn_readfirstlane(__shfl(word_v, ii, 64));
        float sc = __shfl(sco_v, ii, 64);
        int c = word >> 16;
        int n = word & 0xffff;
        if (c != cur) {                       // wave-uniform
            cur = c;
            #pragma unroll
            for (int g = 0; g < 64; ++g) w[g] = Wv[c * (D * D) + g * D + lane];
            ovl = Ov[c * D + lane];
        }
        const float* xr = x + n * D;          // uniform -> scalar loads
        float a = 0.f;
        #pragma unroll
        for (int q = 0; q < 16; ++q) {
            float4 xv = *(const float4*)(xr + q * 4);
            a = fmaf(xv.x, w[4 * q + 0], a);
            a = fmaf(xv.y, w[4 * q + 1], a);
            a = fmaf(xv.z, w[4 * q + 2], a);
            a = fmaf(xv.w, w[4 * q + 3], a);
        }
        unsafeAtomicAdd(out + n * D + lane, sc * (a + ovl));
    }
}

extern "C" void kernel_launch(void* const* d_in, const int* in_sizes, int n_in,
                              void* d_out, int out_size, void* d_ws, size_t ws_size,
                              hipStream_t stream) {
    const float* x    = (const float*)d_in[0];
    const float* ctrs = (const float*)d_in[1];
    const float* Wv   = (const float*)d_in[2];
    const float* Ov   = (const float*)d_in[3];
    float* out = (float*)d_out;

    float* c2       = (float*)d_ws;                    // 512
    int*   hist     = (int*)d_ws + 512;                // 512
    int*   offs     = (int*)d_ws + 1024;               // 513 (reserve 1024)
    int*   cursor   = (int*)d_ws + 2048;               // 512 (reserve 512)
    float* scores   = (float*)d_ws + 2560;             // 262144
    int*   sidx     = (int*)d_ws + 2560 + 262144;      // 262144
    int*   tokentab = (int*)d_ws + 2560 + 2 * 262144;  // 262144
    float* scotab   = (float*)d_ws + 2560 + 3 * 262144;// 262144

    hipLaunchKernelGGL(prep_kernel, dim3(1024), dim3(256), 0, stream,
                       (float4*)out, hist, ctrs, c2);
    hipLaunchKernelGGL(topk5_kernel, dim3(N_TOK / 64), dim3(512), 0, stream,
                       x, ctrs, c2, scores, sidx, hist);
    hipLaunchKernelGGL(scan_kernel, dim3(1), dim3(512), 0, stream, hist, offs, cursor);
    hipLaunchKernelGGL(scatter4_kernel, dim3(256), dim3(256), 0, stream,
                       sidx, scores, cursor, tokentab, scotab);
    hipLaunchKernelGGL(mix4_kernel, dim3(1024), dim3(256), 0, stream,
                       x, Wv, Ov, tokentab, scotab, out);
}